// Round 9
// baseline (57.600 us; speedup 1.0000x reference)
//
#include <hip/hip_runtime.h>

#define BB 4
#define NN 4096
#define DD 128

typedef float vf4 __attribute__((ext_vector_type(4)));

__device__ __forceinline__ float ex2(float x) { return __builtin_amdgcn_exp2f(x); }

// K1: per-row projections in log2 domain. One wave per row.
// si_lg[r] = (x[r]·a1)·log2e ; sj_lg[r] = (x[r]·a2)·log2e
__global__ __launch_bounds__(256) void score_kernel(const float* __restrict__ x,
                                                    const float* __restrict__ a,
                                                    float* __restrict__ si_lg,
                                                    float* __restrict__ sj_lg) {
    const float L2E = 1.4426950408889634f;
    int wave = threadIdx.x >> 6;
    int lane = threadIdx.x & 63;
    int row  = blockIdx.x * 4 + wave;
    const float* xr = x + (size_t)row * DD;
    float x0 = xr[lane];
    float x1 = xr[lane + 64];
    float d1 = x0 * a[lane]      + x1 * a[lane + 64];
    float d2 = x0 * a[DD + lane] + x1 * a[DD + lane + 64];
    #pragma unroll
    for (int off = 1; off < 64; off <<= 1) {
        d1 += __shfl_xor(d1, off, 64);
        d2 += __shfl_xor(d2, off, 64);
    }
    if (lane == 0) {
        si_lg[row] = d1 * L2E;
        sj_lg[row] = d2 * L2E;
    }
}

// K2: one row per wave. Batch s_j plane in 64 VGPRs/lane. Sum pass computes
// p = exp2(max(u+s, 0.2s+v)) ONCE and overwrites sv[] in place (sv is dead
// after the sum pass with one row/wave -> zero extra registers). Write pass
// is the minimum possible: p * inv -> float4 store. No LDS, no barriers,
// plain temporal stores (NT measured -4us in R6).
__global__ __launch_bounds__(256) void softmax_kernel(const float* __restrict__ si_lg,
                                                      const float* __restrict__ sj_lg,
                                                      float* __restrict__ out) {
    const int b    = blockIdx.x >> 10;          // 1024 blocks per batch
    const int wave = threadIdx.x >> 6;
    const int lane = threadIdx.x & 63;
    const int i    = (blockIdx.x & 1023) * 4 + wave;

    // Load entire batch plane: lane holds j = g*256 + lane*4 .. +3 (64 elems).
    const float* sjb = sj_lg + b * NN;
    vf4 sv[16];
    float kmax = -INFINITY;
    #pragma unroll
    for (int g = 0; g < 16; ++g) {
        vf4 s = *reinterpret_cast<const vf4*>(sjb + g * 256 + lane * 4);
        sv[g] = s;
        kmax = fmaxf(fmaxf(fmaxf(s.x, s.y), fmaxf(s.z, s.w)), kmax);
    }
    #pragma unroll
    for (int off = 1; off < 64; off <<= 1)
        kmax = fmaxf(kmax, __shfl_xor(kmax, off, 64));   // covers all of j

    const float si = si_lg[b * NN + i];
    const float c  = si + kmax;
    const float m  = fmaxf(c, 0.2f * c);     // row max in log2 units
    const float u  = si - m;
    const float v  = 0.2f * si - m;

    // Sum pass: compute p once, store back into sv (in-place), accumulate.
    float lsum = 0.f;
    #pragma unroll
    for (int g = 0; g < 16; ++g) {
        vf4 s = sv[g];
        vf4 p;
        p.x = ex2(fmaxf(u + s.x, fmaf(0.2f, s.x, v)));
        p.y = ex2(fmaxf(u + s.y, fmaf(0.2f, s.y, v)));
        p.z = ex2(fmaxf(u + s.z, fmaf(0.2f, s.z, v)));
        p.w = ex2(fmaxf(u + s.w, fmaf(0.2f, s.w, v)));
        sv[g] = p;
        lsum += (p.x + p.y) + (p.z + p.w);
    }
    #pragma unroll
    for (int off = 1; off < 64; off <<= 1)
        lsum += __shfl_xor(lsum, off, 64);
    const float inv = 1.f / lsum;            // denom in [1,4096]

    // Write pass: one multiply per element, nothing else between stores.
    float* orow = out + (size_t)(b * NN + i) * NN;
    #pragma unroll
    for (int g = 0; g < 16; ++g) {
        vf4 p = sv[g];
        vf4 o;
        o.x = p.x * inv;
        o.y = p.y * inv;
        o.z = p.z * inv;
        o.w = p.w * inv;
        *reinterpret_cast<vf4*>(orow + g * 256 + lane * 4) = o;
    }
}

extern "C" void kernel_launch(void* const* d_in, const int* in_sizes, int n_in,
                              void* d_out, int out_size, void* d_ws, size_t ws_size,
                              hipStream_t stream) {
    const float* x = (const float*)d_in[0];
    const float* a = (const float*)d_in[1];
    float* out = (float*)d_out;
    float* si_lg = (float*)d_ws;                 // B*N floats
    float* sj_lg = si_lg + BB * NN;              // B*N floats (128 KB, << ws)

    score_kernel<<<(BB * NN) / 4, 256, 0, stream>>>(x, a, si_lg, sj_lg);
    softmax_kernel<<<(BB * NN) / 4, 256, 0, stream>>>(si_lg, sj_lg, out);
}

// Round 10
// 52.132 us; speedup vs baseline: 1.1049x; 1.1049x over previous
//
#include <hip/hip_runtime.h>

#define BB 4
#define NN 4096
#define DD 128
#define RB 8

typedef float vf4 __attribute__((ext_vector_type(4)));

__device__ __forceinline__ float ex2(float x) { return __builtin_amdgcn_exp2f(x); }

// K1: per-row projections in log2 domain. One wave per row.
// si_lg[r] = (x[r]·a1)·log2e ; sj_lg[r] = (x[r]·a2)·log2e
__global__ __launch_bounds__(256) void score_kernel(const float* __restrict__ x,
                                                    const float* __restrict__ a,
                                                    float* __restrict__ si_lg,
                                                    float* __restrict__ sj_lg) {
    const float L2E = 1.4426950408889634f;
    int wave = threadIdx.x >> 6;
    int lane = threadIdx.x & 63;
    int row  = blockIdx.x * 4 + wave;
    const float* xr = x + (size_t)row * DD;
    float x0 = xr[lane];
    float x1 = xr[lane + 64];
    float d1 = x0 * a[lane]      + x1 * a[lane + 64];
    float d2 = x0 * a[DD + lane] + x1 * a[DD + lane + 64];
    #pragma unroll
    for (int off = 1; off < 64; off <<= 1) {
        d1 += __shfl_xor(d1, off, 64);
        d2 += __shfl_xor(d2, off, 64);
    }
    if (lane == 0) {
        si_lg[row] = d1 * L2E;
        sj_lg[row] = d2 * L2E;
    }
}

// K2 (R7, measured optimum 52.3us): batch s_j plane in 64 VGPRs/lane,
// 2 rows per wave, recompute-in-write-pass (short store dep chains beat
// cached p: R9 measured +5us from extended live ranges). exp2-domain:
//   z = max(u + s, 0.2*s + v)   (leaky via fmax, exact identity)
//   out = exp2(z - log2(sum))   (normalization folded into exponent)
// No LDS, no barriers, plain temporal float4 stores (NT was -4us).
__global__ __launch_bounds__(256) void softmax_kernel(const float* __restrict__ si_lg,
                                                      const float* __restrict__ sj_lg,
                                                      float* __restrict__ out) {
    const int b    = blockIdx.x >> 9;           // 512 blocks per batch
    const int i0   = (blockIdx.x & 511) * RB;
    const int wave = threadIdx.x >> 6;
    const int lane = threadIdx.x & 63;

    // Load entire batch plane: lane holds j = g*256 + lane*4 .. +3 (64 elems).
    const float* sjb = sj_lg + b * NN;
    vf4 sv[16];
    float kmax = -INFINITY;
    #pragma unroll
    for (int g = 0; g < 16; ++g) {
        vf4 s = *reinterpret_cast<const vf4*>(sjb + g * 256 + lane * 4);
        sv[g] = s;
        kmax = fmaxf(fmaxf(fmaxf(s.x, s.y), fmaxf(s.z, s.w)), kmax);
    }
    #pragma unroll
    for (int off = 1; off < 64; off <<= 1)
        kmax = fmaxf(kmax, __shfl_xor(kmax, off, 64));   // covers all of j

    #pragma unroll
    for (int r = 0; r < RB / 4; ++r) {
        const int i = i0 + wave * (RB / 4) + r;
        const float si = si_lg[b * NN + i];
        const float c  = si + kmax;
        const float m  = fmaxf(c, 0.2f * c);     // row max in log2 units
        const float u  = si - m;
        const float v  = 0.2f * si - m;

        float lsum = 0.f;
        #pragma unroll
        for (int g = 0; g < 16; ++g) {
            vf4 s = sv[g];
            lsum += ex2(fmaxf(u + s.x, fmaf(0.2f, s.x, v)))
                  + ex2(fmaxf(u + s.y, fmaf(0.2f, s.y, v)))
                  + ex2(fmaxf(u + s.z, fmaf(0.2f, s.z, v)))
                  + ex2(fmaxf(u + s.w, fmaf(0.2f, s.w, v)));
        }
        #pragma unroll
        for (int off = 1; off < 64; off <<= 1)
            lsum += __shfl_xor(lsum, off, 64);
        const float L  = __builtin_amdgcn_logf(lsum);   // log2(denom), denom in [1,4096]
        const float u2 = u - L;
        const float v2 = v - L;

        float* orow = out + (size_t)(b * NN + i) * NN;
        #pragma unroll
        for (int g = 0; g < 16; ++g) {
            vf4 s = sv[g];
            vf4 o;
            o.x = ex2(fmaxf(u2 + s.x, fmaf(0.2f, s.x, v2)));
            o.y = ex2(fmaxf(u2 + s.y, fmaf(0.2f, s.y, v2)));
            o.z = ex2(fmaxf(u2 + s.z, fmaf(0.2f, s.z, v2)));
            o.w = ex2(fmaxf(u2 + s.w, fmaf(0.2f, s.w, v2)));
            *reinterpret_cast<vf4*>(orow + g * 256 + lane * 4) = o;
        }
    }
}

extern "C" void kernel_launch(void* const* d_in, const int* in_sizes, int n_in,
                              void* d_out, int out_size, void* d_ws, size_t ws_size,
                              hipStream_t stream) {
    const float* x = (const float*)d_in[0];
    const float* a = (const float*)d_in[1];
    float* out = (float*)d_out;
    float* si_lg = (float*)d_ws;                 // B*N floats
    float* sj_lg = si_lg + BB * NN;              // B*N floats (128 KB, << ws)

    score_kernel<<<(BB * NN) / 4, 256, 0, stream>>>(x, a, si_lg, sj_lg);
    softmax_kernel<<<(BB * NN) / RB, 256, 0, stream>>>(si_lg, sj_lg, out);
}